// Round 3
// baseline (1073.740 us; speedup 1.0000x reference)
//
#include <hip/hip_runtime.h>

// ConventionalGNN: 3x (GCNConv -> GraphNorm -> ReLU), N=100000 nodes, E=1.6M edges, D=128.
// Pipeline per layer: GEMM(+fused prev-layer norm/relu) -> bf16 H -> CSR gather (+fused stats).
// CSR built once per call; messages in bf16 to halve gather traffic.

#define EPS_GN 1e-5f

__device__ __forceinline__ float blo(unsigned u) { return __uint_as_float(u << 16); }
__device__ __forceinline__ float bhi(unsigned u) { return __uint_as_float(u & 0xffff0000u); }
__device__ __forceinline__ unsigned bf16rne(float f) {
  unsigned u = __float_as_uint(f);
  u += 0x7fff + ((u >> 16) & 1);
  return u >> 16;
}
__device__ __forceinline__ unsigned packbf(float x, float y) {
  return bf16rne(x) | (bf16rne(y) << 16);
}

// ---------------- CSR build ----------------

__global__ __launch_bounds__(256) void k_count(const int* __restrict__ dst,
                                               int* __restrict__ cnt, int E) {
  int e = blockIdx.x * 256 + threadIdx.x;
  if (e < E) atomicAdd(&cnt[dst[e]], 1);
}

__global__ __launch_bounds__(256) void k_scan1(const int* __restrict__ cnt,
                                               int* __restrict__ rs,
                                               int* __restrict__ bsum, int N) {
  __shared__ int s[256];
  int t = threadIdx.x;
  int base = blockIdx.x * 1024 + t * 4;
  int c0 = (base + 0 < N) ? cnt[base + 0] : 0;
  int c1 = (base + 1 < N) ? cnt[base + 1] : 0;
  int c2 = (base + 2 < N) ? cnt[base + 2] : 0;
  int c3 = (base + 3 < N) ? cnt[base + 3] : 0;
  int tsum = c0 + c1 + c2 + c3;
  s[t] = tsum;
  __syncthreads();
  for (int off = 1; off < 256; off <<= 1) {
    int v = (t >= off) ? s[t - off] : 0;
    __syncthreads();
    s[t] += v;
    __syncthreads();
  }
  int excl = s[t] - tsum;
  if (t == 255) bsum[blockIdx.x] = s[255];
  int e0 = excl, e1 = e0 + c0, e2 = e1 + c1, e3 = e2 + c2;
  if (base + 0 < N) rs[base + 0] = e0;
  if (base + 1 < N) rs[base + 1] = e1;
  if (base + 2 < N) rs[base + 2] = e2;
  if (base + 3 < N) rs[base + 3] = e3;
}

__global__ __launch_bounds__(256) void k_scan2(const int* __restrict__ bsum,
                                               int* __restrict__ boff, int nblk) {
  __shared__ int s[256];
  int t = threadIdx.x;
  int v0 = (t < nblk) ? bsum[t] : 0;
  s[t] = v0;
  __syncthreads();
  for (int off = 1; off < 256; off <<= 1) {
    int v = (t >= off) ? s[t - off] : 0;
    __syncthreads();
    s[t] += v;
    __syncthreads();
  }
  if (t < nblk) boff[t] = s[t] - v0;
}

__global__ __launch_bounds__(256) void k_finalize(const int* __restrict__ cnt,
                                                  const int* __restrict__ boff,
                                                  int* __restrict__ rs,
                                                  int* __restrict__ cursor,
                                                  float* __restrict__ dinv, int N, int E) {
  int i = blockIdx.x * 256 + threadIdx.x;
  if (i == 0) rs[N] = E;
  if (i < N) {
    int v = rs[i] + boff[i >> 10];
    rs[i] = v;
    cursor[i] = v;
    dinv[i] = rsqrtf((float)cnt[i] + 1.0f);
  }
}

// Scatter (src, coef) together as one 8B int2 -> one dirty line per edge.
__global__ __launch_bounds__(256) void k_fill(const int* __restrict__ src,
                                              const int* __restrict__ dst,
                                              const float* __restrict__ dinv,
                                              int* __restrict__ cursor,
                                              int2* __restrict__ csr, int E) {
  int e = blockIdx.x * 256 + threadIdx.x;
  if (e >= E) return;
  int s = src[e], d = dst[e];
  int p = atomicAdd(&cursor[d], 1);
  csr[p] = make_int2(s, __float_as_int(dinv[s] * dinv[d]));
}

// ---------------- Layer kernels ----------------

// H(bf16) = X @ W0, X:[N,4], W0:[4,128]. 4 rows/block; thread = 1 row x 2 cols.
__global__ __launch_bounds__(256) void k_gemm0(const float* __restrict__ X,
                                               const float* __restrict__ W,
                                               unsigned* __restrict__ H, int N) {
  __shared__ float Ws[4 * 128];
  int t = threadIdx.x;
  if (t < 128) {
    Ws[t] = W[t];
    Ws[128 + t] = W[128 + t];
    Ws[256 + t] = W[256 + t];
    Ws[384 + t] = W[384 + t];
  }
  __syncthreads();
  int r = t >> 6, l = t & 63;
  int row = blockIdx.x * 4 + r;
  if (row >= N) return;
  float4 xv = ((const float4*)X)[row];
  int c0 = 2 * l, c1 = 2 * l + 1;
  float v0 = xv.x * Ws[c0] + xv.y * Ws[128 + c0] + xv.z * Ws[256 + c0] + xv.w * Ws[384 + c0];
  float v1 = xv.x * Ws[c1] + xv.y * Ws[128 + c1] + xv.z * Ws[256 + c1] + xv.w * Ws[384 + c1];
  H[(size_t)row * 64 + l] = packbf(v0, v1);
}

// H(bf16) = relu(norm(AGG)) @ W. Norm+relu of the PREVIOUS layer fused into the load.
// A,B per column derived from raw stats (bias folded analytically).
__global__ __launch_bounds__(256) void k_gemm128n(const float* __restrict__ Xagg,
                                                  const float* __restrict__ W,
                                                  const float* __restrict__ stats,
                                                  const float* __restrict__ bias,
                                                  const float* __restrict__ gamma,
                                                  const float* __restrict__ beta,
                                                  const float* __restrict__ alpha,
                                                  unsigned* __restrict__ H, int N, float invN) {
  __shared__ float4 Ws4[128 * 32];  // 64 KiB: W row-major as float4
  __shared__ float As[128], Bs[128];
  int t = threadIdx.x;
  if (t < 128) {
    float s1 = stats[t] * invN, s2 = stats[128 + t] * invN;
    float b = bias[t], a = alpha[t], g = gamma[t], be = beta[t];
    float mu = s1 + b;                      // mean of (agg + b)
    float E2 = s2 + 2.f * b * s1 + b * b;   // E[(agg+b)^2]
    float var = E2 - (2.f * a - a * a) * mu * mu;
    float A = g * rsqrtf(var + EPS_GN);
    As[t] = A;
    Bs[t] = be - A * a * mu + A * b;        // out = A*agg + B
  }
  const float4* W4 = (const float4*)W;
#pragma unroll
  for (int i = 0; i < 16; ++i) Ws4[t + i * 256] = W4[t + i * 256];
  __syncthreads();
  int rg = t >> 4, cg = t & 15;
  int row = blockIdx.x * 16 + rg;
  if (row >= N) return;
  const float4* X4 = (const float4*)(Xagg + (size_t)row * 128);
  float a0x = 0, a0y = 0, a0z = 0, a0w = 0;
  float a1x = 0, a1y = 0, a1z = 0, a1w = 0;
#pragma unroll 4
  for (int k4 = 0; k4 < 32; ++k4) {
    float4 xv = X4[k4];
    float xr[4] = {xv.x, xv.y, xv.z, xv.w};
    float xs[4];
#pragma unroll
    for (int j = 0; j < 4; ++j) {
      int k = k4 * 4 + j;
      float v = fmaf(As[k], xr[j], Bs[k]);
      xs[j] = v > 0.f ? v : 0.f;
    }
#pragma unroll
    for (int j = 0; j < 4; ++j) {
      int k = k4 * 4 + j;
      float4 w0 = Ws4[k * 32 + cg];
      float4 w1 = Ws4[k * 32 + 16 + cg];
      float xsj = xs[j];
      a0x = fmaf(xsj, w0.x, a0x);
      a0y = fmaf(xsj, w0.y, a0y);
      a0z = fmaf(xsj, w0.z, a0z);
      a0w = fmaf(xsj, w0.w, a0w);
      a1x = fmaf(xsj, w1.x, a1x);
      a1y = fmaf(xsj, w1.y, a1y);
      a1z = fmaf(xsj, w1.z, a1z);
      a1w = fmaf(xsj, w1.w, a1w);
    }
  }
  unsigned* Hr = H + (size_t)row * 64;
  ((uint2*)Hr)[cg] = make_uint2(packbf(a0x, a0y), packbf(a0z, a0w));
  ((uint2*)Hr)[16 + cg] = make_uint2(packbf(a1x, a1y), packbf(a1z, a1w));
}

// AGG[n] = H[n]*dinv[n]^2 + sum_{e in csr[n]} H[src]*coef, H in bf16 (256B rows).
// One wave per node, grid-stride; per-block column stats (sum, sumsq) fused.
__global__ __launch_bounds__(256) void k_gather(const unsigned* __restrict__ Hb,
                                                const int* __restrict__ rs,
                                                const int2* __restrict__ csr,
                                                const float* __restrict__ dinv,
                                                float* __restrict__ AGG,
                                                float* __restrict__ stats, int N) {
  int wave = threadIdx.x >> 6, lane = threadIdx.x & 63;
  float s1x = 0.f, s1y = 0.f, s2x = 0.f, s2y = 0.f;
  for (int n = blockIdx.x * 4 + wave; n < N; n += gridDim.x * 4) {
    float di = dinv[n];
    float selfc = di * di;
    unsigned hs = Hb[(size_t)n * 64 + lane];
    float ax = blo(hs) * selfc, ay = bhi(hs) * selfc;
    int j0 = rs[n], j1 = rs[n + 1];
    int len = j1 - j0;
    if (len > 0) {
      int2 eA = csr[j0];
      int2 eB = (len > 1) ? csr[j0 + 1] : eA;
      unsigned hA = Hb[(size_t)eA.x * 64 + lane];
      for (int k = 0; k < len - 1; ++k) {
        int2 eC = (k + 2 < len) ? csr[j0 + k + 2] : eB;          // csr 2 ahead
        unsigned hB = Hb[(size_t)eB.x * 64 + lane];              // row 1 ahead
        float c = __int_as_float(eA.y);
        ax = fmaf(blo(hA), c, ax);
        ay = fmaf(bhi(hA), c, ay);
        eA = eB;
        eB = eC;
        hA = hB;
      }
      float c = __int_as_float(eA.y);
      ax = fmaf(blo(hA), c, ax);
      ay = fmaf(bhi(hA), c, ay);
    }
    ((float2*)AGG)[(size_t)n * 64 + lane] = make_float2(ax, ay);
    s1x += ax;
    s2x = fmaf(ax, ax, s2x);
    s1y += ay;
    s2y = fmaf(ay, ay, s2y);
  }
  __shared__ float shs[4][128];
  __shared__ float shq[4][128];
  shs[wave][2 * lane] = s1x;
  shs[wave][2 * lane + 1] = s1y;
  shq[wave][2 * lane] = s2x;
  shq[wave][2 * lane + 1] = s2y;
  __syncthreads();
  int t = threadIdx.x;
  if (t < 128) {
    float v = shs[0][t] + shs[1][t] + shs[2][t] + shs[3][t];
    atomicAdd(&stats[t], v);
  } else {
    int c = t - 128;
    float v = shq[0][c] + shq[1][c] + shq[2][c] + shq[3][c];
    atomicAdd(&stats[128 + c], v);
  }
}

// Final standalone norm (layer 2) -> d_out. Raw-stats formula, bias folded.
__global__ __launch_bounds__(256) void k_norm(const float* __restrict__ AGG,
                                              const float* __restrict__ stats,
                                              const float* __restrict__ bias,
                                              const float* __restrict__ gamma,
                                              const float* __restrict__ beta,
                                              const float* __restrict__ alpha,
                                              float* __restrict__ OUT, int N, float invN) {
  int i = blockIdx.x * 256 + threadIdx.x;  // float4 index
  if (i >= N * 32) return;
  int c4 = i & 31;
  float4 v = ((const float4*)AGG)[i];
  float vv[4] = {v.x, v.y, v.z, v.w};
  float ov[4];
#pragma unroll
  for (int j = 0; j < 4; ++j) {
    int c = c4 * 4 + j;
    float s1 = stats[c] * invN, s2 = stats[128 + c] * invN;
    float b = bias[c], a = alpha[c], g = gamma[c], be = beta[c];
    float mu = s1 + b;
    float E2 = s2 + 2.f * b * s1 + b * b;
    float var = E2 - (2.f * a - a * a) * mu * mu;
    float A = g * rsqrtf(var + EPS_GN);
    float B = be - A * a * mu + A * b;
    float o = fmaf(A, vv[j], B);
    ov[j] = o > 0.f ? o : 0.f;
  }
  ((float4*)OUT)[i] = make_float4(ov[0], ov[1], ov[2], ov[3]);
}

// ---------------- Launch ----------------

extern "C" void kernel_launch(void* const* d_in, const int* in_sizes, int n_in,
                              void* d_out, int out_size, void* d_ws, size_t ws_size,
                              hipStream_t stream) {
  const float* x = (const float*)d_in[0];
  const int* ei = (const int*)d_in[1];
  const float* W0 = (const float*)d_in[2];
  const float* b0 = (const float*)d_in[3];
  const float* W12 = (const float*)d_in[4];
  const float* b12 = (const float*)d_in[5];
  const float* gamma = (const float*)d_in[6];
  const float* beta = (const float*)d_in[7];
  const float* alpha = (const float*)d_in[8];
  float* out = (float*)d_out;

  int N = in_sizes[0] / 4;
  int E = in_sizes[1] / 2;
  const int* srcArr = ei;
  const int* dstArr = ei + E;

  char* w = (char*)d_ws;
  auto alloc = [&](size_t bytes) {
    char* p = w;
    w += (bytes + 255) & ~(size_t)255;
    return p;
  };
  int* cnt = (int*)alloc((size_t)N * 4);
  float* stats = (float*)alloc(3 * 256 * 4);  // [layer][sum(128)|sumsq(128)] - adjacent to cnt
  int* rs = (int*)alloc(((size_t)N + 1) * 4);
  int* cursor = (int*)alloc((size_t)N * 4);
  int* bsum = (int*)alloc(512);
  int* boff = (int*)alloc(512);
  int2* csr = (int2*)alloc((size_t)E * 8);
  float* dinv = (float*)alloc((size_t)N * 4);
  unsigned* Hb = (unsigned*)alloc((size_t)N * 64 * 4);  // bf16 H, 25.6 MB
  float* AGG = (float*)alloc((size_t)N * 128 * 4);      // fp32 agg, 51.2 MB

  // zero cnt + all stats (contiguous region)
  size_t zlen = (size_t)((char*)stats - (char*)cnt) + 3 * 256 * 4;
  hipMemsetAsync(cnt, 0, zlen, stream);

  int nblk = (N + 1023) / 1024;
  k_count<<<(E + 255) / 256, 256, 0, stream>>>(dstArr, cnt, E);
  k_scan1<<<nblk, 256, 0, stream>>>(cnt, rs, bsum, N);
  k_scan2<<<1, 256, 0, stream>>>(bsum, boff, nblk);
  k_finalize<<<(N + 255) / 256, 256, 0, stream>>>(cnt, boff, rs, cursor, dinv, N, E);
  k_fill<<<(E + 255) / 256, 256, 0, stream>>>(srcArr, dstArr, dinv, cursor, csr, E);

  float invN = 1.0f / (float)N;
  int gGemm = (N + 15) / 16;

  // Layer 0
  k_gemm0<<<(N + 3) / 4, 256, 0, stream>>>(x, W0, Hb, N);
  k_gather<<<2048, 256, 0, stream>>>(Hb, rs, csr, dinv, AGG, stats, N);
  // Layer 1 (norm of layer 0 fused into gemm load)
  k_gemm128n<<<gGemm, 256, 0, stream>>>(AGG, W12, stats, b0, gamma, beta, alpha, Hb, N, invN);
  k_gather<<<2048, 256, 0, stream>>>(Hb, rs, csr, dinv, AGG, stats + 256, N);
  // Layer 2
  k_gemm128n<<<gGemm, 256, 0, stream>>>(AGG, W12 + 16384, stats + 256, b12, gamma + 128,
                                        beta + 128, alpha + 128, Hb, N, invN);
  k_gather<<<2048, 256, 0, stream>>>(Hb, rs, csr, dinv, AGG, stats + 512, N);
  // Final norm -> out
  k_norm<<<(N * 32 + 255) / 256, 256, 0, stream>>>(AGG, stats + 512, b12 + 128, gamma + 256,
                                                   beta + 256, alpha + 256, out, N, invN);
}

// Round 4
// 830.300 us; speedup vs baseline: 1.2932x; 1.2932x over previous
//
#include <hip/hip_runtime.h>

// ConventionalGNN: 3x (GCNConv -> GraphNorm -> ReLU), N=100000 nodes, E=1.6M edges, D=128.
// H is stored pre-scaled by dinv (Hs = dinv*h, bf16): AGG[n] = dinv[n]*(sum Hs[src] + Hs[n]).
// CSR payload = src only (4B/edge). Gather: 16 lanes per row (dwordx4), 4 edges in flight
// per wave instruction, 2-deep rotating prefetch -> 4x in-flight bytes vs 1-edge/wave.

#define EPS_GN 1e-5f

__device__ __forceinline__ float blo(unsigned u) { return __uint_as_float(u << 16); }
__device__ __forceinline__ float bhi(unsigned u) { return __uint_as_float(u & 0xffff0000u); }
__device__ __forceinline__ unsigned bf16rne(float f) {
  unsigned u = __float_as_uint(f);
  u += 0x7fff + ((u >> 16) & 1);
  return u >> 16;
}
__device__ __forceinline__ unsigned packbf(float x, float y) {
  return bf16rne(x) | (bf16rne(y) << 16);
}

// ---------------- CSR build ----------------

__global__ __launch_bounds__(256) void k_count(const int* __restrict__ dst,
                                               int* __restrict__ cnt, int E) {
  int e = blockIdx.x * 256 + threadIdx.x;
  if (e < E) atomicAdd(&cnt[dst[e]], 1);
}

__global__ __launch_bounds__(256) void k_scan1(const int* __restrict__ cnt,
                                               int* __restrict__ rs,
                                               int* __restrict__ bsum, int N) {
  __shared__ int s[256];
  int t = threadIdx.x;
  int base = blockIdx.x * 1024 + t * 4;
  int c0 = (base + 0 < N) ? cnt[base + 0] : 0;
  int c1 = (base + 1 < N) ? cnt[base + 1] : 0;
  int c2 = (base + 2 < N) ? cnt[base + 2] : 0;
  int c3 = (base + 3 < N) ? cnt[base + 3] : 0;
  int tsum = c0 + c1 + c2 + c3;
  s[t] = tsum;
  __syncthreads();
  for (int off = 1; off < 256; off <<= 1) {
    int v = (t >= off) ? s[t - off] : 0;
    __syncthreads();
    s[t] += v;
    __syncthreads();
  }
  int excl = s[t] - tsum;
  if (t == 255) bsum[blockIdx.x] = s[255];
  int e0 = excl, e1 = e0 + c0, e2 = e1 + c1, e3 = e2 + c2;
  if (base + 0 < N) rs[base + 0] = e0;
  if (base + 1 < N) rs[base + 1] = e1;
  if (base + 2 < N) rs[base + 2] = e2;
  if (base + 3 < N) rs[base + 3] = e3;
}

__global__ __launch_bounds__(256) void k_scan2(const int* __restrict__ bsum,
                                               int* __restrict__ boff, int nblk) {
  __shared__ int s[256];
  int t = threadIdx.x;
  int v0 = (t < nblk) ? bsum[t] : 0;
  s[t] = v0;
  __syncthreads();
  for (int off = 1; off < 256; off <<= 1) {
    int v = (t >= off) ? s[t - off] : 0;
    __syncthreads();
    s[t] += v;
    __syncthreads();
  }
  if (t < nblk) boff[t] = s[t] - v0;
}

__global__ __launch_bounds__(256) void k_finalize(const int* __restrict__ cnt,
                                                  const int* __restrict__ boff,
                                                  int* __restrict__ rs,
                                                  int* __restrict__ cursor,
                                                  float* __restrict__ dinv, int N, int E) {
  int i = blockIdx.x * 256 + threadIdx.x;
  if (i == 0) rs[N] = E;
  if (i < N) {
    int v = rs[i] + boff[i >> 10];
    rs[i] = v;
    cursor[i] = v;
    dinv[i] = rsqrtf((float)cnt[i] + 1.0f);
  }
}

// Scatter src only (4B per edge).
__global__ __launch_bounds__(256) void k_fill(const int* __restrict__ src,
                                              const int* __restrict__ dst,
                                              int* __restrict__ cursor,
                                              int* __restrict__ csr, int E) {
  int e = blockIdx.x * 256 + threadIdx.x;
  if (e >= E) return;
  int s = src[e], d = dst[e];
  int p = atomicAdd(&cursor[d], 1);
  csr[p] = s;
}

// ---------------- Layer kernels ----------------

// Hs(bf16) = dinv * (X @ W0). 4 rows/block; thread = 1 row x 2 cols.
__global__ __launch_bounds__(256) void k_gemm0(const float* __restrict__ X,
                                               const float* __restrict__ W,
                                               const float* __restrict__ dinv,
                                               unsigned* __restrict__ H, int N) {
  __shared__ float Ws[4 * 128];
  int t = threadIdx.x;
  if (t < 128) {
    Ws[t] = W[t];
    Ws[128 + t] = W[128 + t];
    Ws[256 + t] = W[256 + t];
    Ws[384 + t] = W[384 + t];
  }
  __syncthreads();
  int r = t >> 6, l = t & 63;
  int row = blockIdx.x * 4 + r;
  if (row >= N) return;
  float4 xv = ((const float4*)X)[row];
  float di = dinv[row];
  int c0 = 2 * l, c1 = 2 * l + 1;
  float v0 = xv.x * Ws[c0] + xv.y * Ws[128 + c0] + xv.z * Ws[256 + c0] + xv.w * Ws[384 + c0];
  float v1 = xv.x * Ws[c1] + xv.y * Ws[128 + c1] + xv.z * Ws[256 + c1] + xv.w * Ws[384 + c1];
  H[(size_t)row * 64 + l] = packbf(di * v0, di * v1);
}

// Hs(bf16) = dinv * (relu(norm(AGG)) @ W). Prev-layer norm+relu fused into the load.
__global__ __launch_bounds__(256) void k_gemm128n(const float* __restrict__ Xagg,
                                                  const float* __restrict__ W,
                                                  const float* __restrict__ stats,
                                                  const float* __restrict__ bias,
                                                  const float* __restrict__ gamma,
                                                  const float* __restrict__ beta,
                                                  const float* __restrict__ alpha,
                                                  const float* __restrict__ dinv,
                                                  unsigned* __restrict__ H, int N, float invN) {
  __shared__ float4 Ws4[128 * 32];  // 64 KiB: W row-major as float4
  __shared__ float As[128], Bs[128];
  int t = threadIdx.x;
  if (t < 128) {
    float s1 = stats[t] * invN, s2 = stats[128 + t] * invN;
    float b = bias[t], a = alpha[t], g = gamma[t], be = beta[t];
    float mu = s1 + b;                     // mean of (agg + b)
    float E2 = s2 + 2.f * b * s1 + b * b;  // E[(agg+b)^2]
    float var = E2 - (2.f * a - a * a) * mu * mu;
    float A = g * rsqrtf(var + EPS_GN);
    As[t] = A;
    Bs[t] = be - A * a * mu + A * b;  // out = A*agg + B
  }
  const float4* W4 = (const float4*)W;
#pragma unroll
  for (int i = 0; i < 16; ++i) Ws4[t + i * 256] = W4[t + i * 256];
  __syncthreads();
  int rg = t >> 4, cg = t & 15;
  int row = blockIdx.x * 16 + rg;
  if (row >= N) return;
  const float4* X4 = (const float4*)(Xagg + (size_t)row * 128);
  float a0x = 0, a0y = 0, a0z = 0, a0w = 0;
  float a1x = 0, a1y = 0, a1z = 0, a1w = 0;
#pragma unroll 4
  for (int k4 = 0; k4 < 32; ++k4) {
    float4 xv = X4[k4];
    float xr[4] = {xv.x, xv.y, xv.z, xv.w};
    float xs[4];
#pragma unroll
    for (int j = 0; j < 4; ++j) {
      int k = k4 * 4 + j;
      float v = fmaf(As[k], xr[j], Bs[k]);
      xs[j] = v > 0.f ? v : 0.f;
    }
#pragma unroll
    for (int j = 0; j < 4; ++j) {
      int k = k4 * 4 + j;
      float4 w0 = Ws4[k * 32 + cg];
      float4 w1 = Ws4[k * 32 + 16 + cg];
      float xsj = xs[j];
      a0x = fmaf(xsj, w0.x, a0x);
      a0y = fmaf(xsj, w0.y, a0y);
      a0z = fmaf(xsj, w0.z, a0z);
      a0w = fmaf(xsj, w0.w, a0w);
      a1x = fmaf(xsj, w1.x, a1x);
      a1y = fmaf(xsj, w1.y, a1y);
      a1z = fmaf(xsj, w1.z, a1z);
      a1w = fmaf(xsj, w1.w, a1w);
    }
  }
  float di = dinv[row];
  unsigned* Hr = H + (size_t)row * 64;
  ((uint2*)Hr)[cg] = make_uint2(packbf(di * a0x, di * a0y), packbf(di * a0z, di * a0w));
  ((uint2*)Hr)[16 + cg] = make_uint2(packbf(di * a1x, di * a1y), packbf(di * a1z, di * a1w));
}

// AGG[n] = dinv[n] * (Hs[n] + sum_{e in csr[n]} Hs[src]). Hs bf16, rows 256B (16 uint4).
// Wave = 1 node; 16-lane group g handles virtual edge b*4+g-1 (-1 = self, >=len = zero row N).
// 2-deep rotating prefetch; shfl_xor butterfly combine; fused per-block column stats.
__global__ __launch_bounds__(256) void k_gather(const uint4* __restrict__ H4,
                                                const int* __restrict__ rs,
                                                const int* __restrict__ csr,
                                                const float* __restrict__ dinv,
                                                float* __restrict__ AGG,
                                                float* __restrict__ stats, int N) {
  int wave = threadIdx.x >> 6, lane = threadIdx.x & 63;
  int g = lane >> 4, sl = lane & 15;
  float s1a = 0.f, s1b = 0.f, s2a = 0.f, s2b = 0.f;
  for (int n = blockIdx.x * 4 + wave; n < N; n += gridDim.x * 4) {
    int j0 = rs[n], j1 = rs[n + 1];
    int len = j1 - j0;
    int nb = (len + 4) >> 2;  // batches covering len+1 virtual edges
    float acc[8];
#pragma unroll
    for (int i = 0; i < 8; ++i) acc[i] = 0.f;

    auto vsrc = [&](int b) -> int {
      int idx = b * 4 + g - 1;
      int jj = j0 + idx;
      jj = min(jj, j1 - 1);
      jj = max(jj, j0);
      int c = csr[jj];
      return (idx < 0) ? n : ((idx < len) ? c : N);
    };

    uint4 hA = H4[(size_t)vsrc(0) * 16 + sl];
    uint4 hB, hC;
    if (nb > 1) hB = H4[(size_t)vsrc(1) * 16 + sl];
    for (int b = 0; b < nb; ++b) {
      if (b + 2 < nb) hC = H4[(size_t)vsrc(b + 2) * 16 + sl];
      unsigned uu[4] = {hA.x, hA.y, hA.z, hA.w};
#pragma unroll
      for (int i = 0; i < 4; ++i) {
        acc[2 * i] += blo(uu[i]);
        acc[2 * i + 1] += bhi(uu[i]);
      }
      hA = hB;
      hB = hC;
    }
    // butterfly: every lane ends with the full column sums
#pragma unroll
    for (int i = 0; i < 8; ++i) {
      acc[i] += __shfl_xor(acc[i], 16);
      acc[i] += __shfl_xor(acc[i], 32);
    }
    float dn = dinv[n];
    float v0 = acc[2 * g] * dn;
    float v1 = acc[2 * g + 1] * dn;
    ((float2*)(AGG + (size_t)n * 128))[sl * 4 + g] = make_float2(v0, v1);
    s1a += v0;
    s2a = fmaf(v0, v0, s2a);
    s1b += v1;
    s2b = fmaf(v1, v1, s2b);
  }
  __shared__ float sh[4][256];
  int col = sl * 8 + g * 2;
  sh[wave][col] = s1a;
  sh[wave][col + 1] = s1b;
  sh[wave][128 + col] = s2a;
  sh[wave][128 + col + 1] = s2b;
  __syncthreads();
  int t = threadIdx.x;
  float v = sh[0][t] + sh[1][t] + sh[2][t] + sh[3][t];
  atomicAdd(&stats[t], v);
}

// Final standalone norm (layer 2) -> d_out. Raw-stats formula, bias folded.
__global__ __launch_bounds__(256) void k_norm(const float* __restrict__ AGG,
                                              const float* __restrict__ stats,
                                              const float* __restrict__ bias,
                                              const float* __restrict__ gamma,
                                              const float* __restrict__ beta,
                                              const float* __restrict__ alpha,
                                              float* __restrict__ OUT, int N, float invN) {
  int i = blockIdx.x * 256 + threadIdx.x;  // float4 index
  if (i >= N * 32) return;
  int c4 = i & 31;
  float4 v = ((const float4*)AGG)[i];
  float vv[4] = {v.x, v.y, v.z, v.w};
  float ov[4];
#pragma unroll
  for (int j = 0; j < 4; ++j) {
    int c = c4 * 4 + j;
    float s1 = stats[c] * invN, s2 = stats[128 + c] * invN;
    float b = bias[c], a = alpha[c], g = gamma[c], be = beta[c];
    float mu = s1 + b;
    float E2 = s2 + 2.f * b * s1 + b * b;
    float var = E2 - (2.f * a - a * a) * mu * mu;
    float A = g * rsqrtf(var + EPS_GN);
    float B = be - A * a * mu + A * b;
    float o = fmaf(A, vv[j], B);
    ov[j] = o > 0.f ? o : 0.f;
  }
  ((float4*)OUT)[i] = make_float4(ov[0], ov[1], ov[2], ov[3]);
}

// ---------------- Launch ----------------

extern "C" void kernel_launch(void* const* d_in, const int* in_sizes, int n_in,
                              void* d_out, int out_size, void* d_ws, size_t ws_size,
                              hipStream_t stream) {
  const float* x = (const float*)d_in[0];
  const int* ei = (const int*)d_in[1];
  const float* W0 = (const float*)d_in[2];
  const float* b0 = (const float*)d_in[3];
  const float* W12 = (const float*)d_in[4];
  const float* b12 = (const float*)d_in[5];
  const float* gamma = (const float*)d_in[6];
  const float* beta = (const float*)d_in[7];
  const float* alpha = (const float*)d_in[8];
  float* out = (float*)d_out;

  int N = in_sizes[0] / 4;
  int E = in_sizes[1] / 2;
  const int* srcArr = ei;
  const int* dstArr = ei + E;

  char* w = (char*)d_ws;
  auto alloc = [&](size_t bytes) {
    char* p = w;
    w += (bytes + 255) & ~(size_t)255;
    return p;
  };
  int* cnt = (int*)alloc((size_t)N * 4);
  float* stats = (float*)alloc(3 * 256 * 4);  // [layer][sum(128)|sumsq(128)] - adjacent to cnt
  int* rs = (int*)alloc(((size_t)N + 1) * 4);
  int* cursor = (int*)alloc((size_t)N * 4);
  int* bsum = (int*)alloc(512);
  int* boff = (int*)alloc(512);
  int* csr = (int*)alloc(((size_t)E + 8) * 4);          // src only, padded
  float* dinv = (float*)alloc((size_t)N * 4);
  unsigned* Hb = (unsigned*)alloc(((size_t)N + 1) * 64 * 4);  // bf16 Hs, row N = zeros
  float* AGG = (float*)alloc((size_t)N * 128 * 4);            // fp32 agg

  // zero cnt + all stats (contiguous region), and the zero-row of Hb
  size_t zlen = (size_t)((char*)stats - (char*)cnt) + 3 * 256 * 4;
  hipMemsetAsync(cnt, 0, zlen, stream);
  hipMemsetAsync(Hb + (size_t)N * 64, 0, 256, stream);

  int nblk = (N + 1023) / 1024;
  k_count<<<(E + 255) / 256, 256, 0, stream>>>(dstArr, cnt, E);
  k_scan1<<<nblk, 256, 0, stream>>>(cnt, rs, bsum, N);
  k_scan2<<<1, 256, 0, stream>>>(bsum, boff, nblk);
  k_finalize<<<(N + 255) / 256, 256, 0, stream>>>(cnt, boff, rs, cursor, dinv, N, E);
  k_fill<<<(E + 255) / 256, 256, 0, stream>>>(srcArr, dstArr, cursor, csr, E);

  float invN = 1.0f / (float)N;
  int gGemm = (N + 15) / 16;
  const uint4* H4 = (const uint4*)Hb;

  // Layer 0
  k_gemm0<<<(N + 3) / 4, 256, 0, stream>>>(x, W0, dinv, Hb, N);
  k_gather<<<2048, 256, 0, stream>>>(H4, rs, csr, dinv, AGG, stats, N);
  // Layer 1 (norm of layer 0 fused into gemm load)
  k_gemm128n<<<gGemm, 256, 0, stream>>>(AGG, W12, stats, b0, gamma, beta, alpha, dinv, Hb, N, invN);
  k_gather<<<2048, 256, 0, stream>>>(H4, rs, csr, dinv, AGG, stats + 256, N);
  // Layer 2
  k_gemm128n<<<gGemm, 256, 0, stream>>>(AGG, W12 + 16384, stats + 256, b12, gamma + 128,
                                        beta + 128, alpha + 128, dinv, Hb, N, invN);
  k_gather<<<2048, 256, 0, stream>>>(H4, rs, csr, dinv, AGG, stats + 512, N);
  // Final norm -> out
  k_norm<<<(N * 32 + 255) / 256, 256, 0, stream>>>(AGG, stats + 512, b12 + 128, gamma + 256,
                                                   beta + 256, alpha + 256, out, N, invN);
}

// Round 5
// 786.761 us; speedup vs baseline: 1.3648x; 1.0553x over previous
//
#include <hip/hip_runtime.h>

// ConventionalGNN: 3x (GCNConv -> GraphNorm -> ReLU), N=100000 nodes, E=1.6M edges, D=128.
// Hs = dinv*h in bf16; AGG[n] = dinv[n]*(sum Hs[src] + Hs[n]), stored bf16.
// CSR build: XCD-partitioned count/fill (blockIdx&7 = node-range partition) so scattered
// cnt/csr lines stay in one XCD's L2 (kills cross-XCD line migration writebacks).
// Gather: 16 lanes/row (dwordx4), 4 edges per wave-instruction, 3-deep rotating prefetch.

#define EPS_GN 1e-5f

__device__ __forceinline__ float blo(unsigned u) { return __uint_as_float(u << 16); }
__device__ __forceinline__ float bhi(unsigned u) { return __uint_as_float(u & 0xffff0000u); }
__device__ __forceinline__ unsigned bf16rne(float f) {
  unsigned u = __float_as_uint(f);
  u += 0x7fff + ((u >> 16) & 1);
  return u >> 16;
}
__device__ __forceinline__ unsigned packbf(float x, float y) {
  return bf16rne(x) | (bf16rne(y) << 16);
}

// ---------------- CSR build ----------------

// XCD-partitioned degree count: partition p = blockIdx&7 owns dst in [N*p/8, N*(p+1)/8).
__global__ __launch_bounds__(256) void k_count_p(const int* __restrict__ dst,
                                                 int* __restrict__ cnt, int E, int N) {
  int p = blockIdx.x & 7;
  int lo = (int)((long long)N * p >> 3), hi = (int)((long long)N * (p + 1) >> 3);
  int stride = (gridDim.x >> 3) * 256;
  for (int e = (blockIdx.x >> 3) * 256 + threadIdx.x; e < E; e += stride) {
    int d = dst[e];
    if (d >= lo && d < hi) atomicAdd(&cnt[d], 1);
  }
}

__global__ __launch_bounds__(256) void k_scan1(const int* __restrict__ cnt,
                                               int* __restrict__ rs,
                                               int* __restrict__ bsum, int N) {
  __shared__ int s[256];
  int t = threadIdx.x;
  int base = blockIdx.x * 1024 + t * 4;
  int c0 = (base + 0 < N) ? cnt[base + 0] : 0;
  int c1 = (base + 1 < N) ? cnt[base + 1] : 0;
  int c2 = (base + 2 < N) ? cnt[base + 2] : 0;
  int c3 = (base + 3 < N) ? cnt[base + 3] : 0;
  int tsum = c0 + c1 + c2 + c3;
  s[t] = tsum;
  __syncthreads();
  for (int off = 1; off < 256; off <<= 1) {
    int v = (t >= off) ? s[t - off] : 0;
    __syncthreads();
    s[t] += v;
    __syncthreads();
  }
  int excl = s[t] - tsum;
  if (t == 255) bsum[blockIdx.x] = s[255];
  int e0 = excl, e1 = e0 + c0, e2 = e1 + c1, e3 = e2 + c2;
  if (base + 0 < N) rs[base + 0] = e0;
  if (base + 1 < N) rs[base + 1] = e1;
  if (base + 2 < N) rs[base + 2] = e2;
  if (base + 3 < N) rs[base + 3] = e3;
}

__global__ __launch_bounds__(256) void k_scan2(const int* __restrict__ bsum,
                                               int* __restrict__ boff, int nblk) {
  __shared__ int s[256];
  int t = threadIdx.x;
  int v0 = (t < nblk) ? bsum[t] : 0;
  s[t] = v0;
  __syncthreads();
  for (int off = 1; off < 256; off <<= 1) {
    int v = (t >= off) ? s[t - off] : 0;
    __syncthreads();
    s[t] += v;
    __syncthreads();
  }
  if (t < nblk) boff[t] = s[t] - v0;
}

__global__ __launch_bounds__(256) void k_finalize(const int* __restrict__ cnt,
                                                  const int* __restrict__ boff,
                                                  int* __restrict__ rs,
                                                  int* __restrict__ cursor,
                                                  float* __restrict__ dinv, int N, int E) {
  int i = blockIdx.x * 256 + threadIdx.x;
  if (i == 0) rs[N] = E;
  if (i < N) {
    int v = rs[i] + boff[i >> 10];
    rs[i] = v;
    cursor[i] = v;
    dinv[i] = rsqrtf((float)cnt[i] + 1.0f);
  }
}

// XCD-partitioned fill: csr lines for a node range written by one partition group only.
__global__ __launch_bounds__(256) void k_fill_p(const int* __restrict__ src,
                                                const int* __restrict__ dst,
                                                int* __restrict__ cursor,
                                                int* __restrict__ csr, int E, int N) {
  int p = blockIdx.x & 7;
  int lo = (int)((long long)N * p >> 3), hi = (int)((long long)N * (p + 1) >> 3);
  int stride = (gridDim.x >> 3) * 256;
  for (int e = (blockIdx.x >> 3) * 256 + threadIdx.x; e < E; e += stride) {
    int d = dst[e];
    if (d >= lo && d < hi) {
      int pos = atomicAdd(&cursor[d], 1);
      csr[pos] = src[e];
    }
  }
}

// ---------------- Layer kernels ----------------

// Hs(bf16) = dinv * (X @ W0). 4 rows/block; thread = 1 row x 2 cols.
__global__ __launch_bounds__(256) void k_gemm0(const float* __restrict__ X,
                                               const float* __restrict__ W,
                                               const float* __restrict__ dinv,
                                               unsigned* __restrict__ H, int N) {
  __shared__ float Ws[4 * 128];
  int t = threadIdx.x;
  if (t < 128) {
    Ws[t] = W[t];
    Ws[128 + t] = W[128 + t];
    Ws[256 + t] = W[256 + t];
    Ws[384 + t] = W[384 + t];
  }
  __syncthreads();
  int r = t >> 6, l = t & 63;
  int row = blockIdx.x * 4 + r;
  if (row >= N) return;
  float4 xv = ((const float4*)X)[row];
  float di = dinv[row];
  int c0 = 2 * l, c1 = 2 * l + 1;
  float v0 = xv.x * Ws[c0] + xv.y * Ws[128 + c0] + xv.z * Ws[256 + c0] + xv.w * Ws[384 + c0];
  float v1 = xv.x * Ws[c1] + xv.y * Ws[128 + c1] + xv.z * Ws[256 + c1] + xv.w * Ws[384 + c1];
  H[(size_t)row * 64 + l] = packbf(di * v0, di * v1);
}

// Hs(bf16) = dinv * (relu(norm(AGGb)) @ W). Prev-layer norm+relu fused into the load.
// AGGb is bf16 (row = 16 uint4). A,B per column derived from raw fp32 stats.
__global__ __launch_bounds__(256) void k_gemm128n(const unsigned* __restrict__ AGGb,
                                                  const float* __restrict__ W,
                                                  const float* __restrict__ stats,
                                                  const float* __restrict__ bias,
                                                  const float* __restrict__ gamma,
                                                  const float* __restrict__ beta,
                                                  const float* __restrict__ alpha,
                                                  const float* __restrict__ dinv,
                                                  unsigned* __restrict__ H, int N, float invN) {
  __shared__ float4 Ws4[128 * 32];  // 64 KiB: W row-major as float4
  __shared__ float As[128], Bs[128];
  int t = threadIdx.x;
  if (t < 128) {
    float s1 = stats[t] * invN, s2 = stats[128 + t] * invN;
    float b = bias[t], a = alpha[t], g = gamma[t], be = beta[t];
    float mu = s1 + b;                     // mean of (agg + b)
    float E2 = s2 + 2.f * b * s1 + b * b;  // E[(agg+b)^2]
    float var = E2 - (2.f * a - a * a) * mu * mu;
    float A = g * rsqrtf(var + EPS_GN);
    As[t] = A;
    Bs[t] = be - A * a * mu + A * b;  // out = A*agg + B
  }
  const float4* W4 = (const float4*)W;
#pragma unroll
  for (int i = 0; i < 16; ++i) Ws4[t + i * 256] = W4[t + i * 256];
  __syncthreads();
  int rg = t >> 4, cg = t & 15;
  int row = blockIdx.x * 16 + rg;
  if (row >= N) return;
  const uint4* X4 = (const uint4*)(AGGb + (size_t)row * 64);
  float a0x = 0, a0y = 0, a0z = 0, a0w = 0;
  float a1x = 0, a1y = 0, a1z = 0, a1w = 0;
#pragma unroll 2
  for (int k8 = 0; k8 < 16; ++k8) {
    uint4 xv = X4[k8];
    float xr[8] = {blo(xv.x), bhi(xv.x), blo(xv.y), bhi(xv.y),
                   blo(xv.z), bhi(xv.z), blo(xv.w), bhi(xv.w)};
    float xs[8];
#pragma unroll
    for (int j = 0; j < 8; ++j) {
      int k = k8 * 8 + j;
      float v = fmaf(As[k], xr[j], Bs[k]);
      xs[j] = v > 0.f ? v : 0.f;
    }
#pragma unroll
    for (int j = 0; j < 8; ++j) {
      int k = k8 * 8 + j;
      float4 w0 = Ws4[k * 32 + cg];
      float4 w1 = Ws4[k * 32 + 16 + cg];
      float xsj = xs[j];
      a0x = fmaf(xsj, w0.x, a0x);
      a0y = fmaf(xsj, w0.y, a0y);
      a0z = fmaf(xsj, w0.z, a0z);
      a0w = fmaf(xsj, w0.w, a0w);
      a1x = fmaf(xsj, w1.x, a1x);
      a1y = fmaf(xsj, w1.y, a1y);
      a1z = fmaf(xsj, w1.z, a1z);
      a1w = fmaf(xsj, w1.w, a1w);
    }
  }
  float di = dinv[row];
  unsigned* Hr = H + (size_t)row * 64;
  ((uint2*)Hr)[cg] = make_uint2(packbf(di * a0x, di * a0y), packbf(di * a0z, di * a0w));
  ((uint2*)Hr)[16 + cg] = make_uint2(packbf(di * a1x, di * a1y), packbf(di * a1z, di * a1w));
}

// AGGb[n](bf16) = dinv[n] * (Hs[n] + sum_{e in csr[n]} Hs[src]). Hs bf16, rows 256B (16 uint4).
// Wave = 1 node; 16-lane group g handles virtual edge b*4+g-1 (-1 = self, >=len = zero row N).
// 3-deep rotating prefetch; shfl_xor butterfly combine; fused per-block column stats (fp32).
__global__ __launch_bounds__(256) void k_gather(const uint4* __restrict__ H4,
                                                const int* __restrict__ rs,
                                                const int* __restrict__ csr,
                                                const float* __restrict__ dinv,
                                                unsigned* __restrict__ AGGb,
                                                float* __restrict__ stats, int N) {
  int wave = threadIdx.x >> 6, lane = threadIdx.x & 63;
  int g = lane >> 4, sl = lane & 15;
  float s1a = 0.f, s1b = 0.f, s2a = 0.f, s2b = 0.f;
  for (int n = blockIdx.x * 4 + wave; n < N; n += gridDim.x * 4) {
    int j0 = rs[n], j1 = rs[n + 1];
    int len = j1 - j0;
    int nb = (len + 4) >> 2;  // batches covering len+1 virtual edges
    float acc[8];
#pragma unroll
    for (int i = 0; i < 8; ++i) acc[i] = 0.f;

    auto vsrc = [&](int b) -> int {
      int idx = b * 4 + g - 1;
      int jj = j0 + idx;
      jj = min(jj, j1 - 1);
      jj = max(jj, j0);
      int c = csr[jj];
      return (idx < 0) ? n : ((idx < len) ? c : N);
    };

    uint4 hA = H4[(size_t)vsrc(0) * 16 + sl];
    uint4 hB, hC, hD;
    if (nb > 1) hB = H4[(size_t)vsrc(1) * 16 + sl];
    if (nb > 2) hC = H4[(size_t)vsrc(2) * 16 + sl];
    for (int b = 0; b < nb; ++b) {
      if (b + 3 < nb) hD = H4[(size_t)vsrc(b + 3) * 16 + sl];
      unsigned uu[4] = {hA.x, hA.y, hA.z, hA.w};
#pragma unroll
      for (int i = 0; i < 4; ++i) {
        acc[2 * i] += blo(uu[i]);
        acc[2 * i + 1] += bhi(uu[i]);
      }
      hA = hB;
      hB = hC;
      hC = hD;
    }
    // butterfly: every lane ends with the full column sums for its sl-slice
#pragma unroll
    for (int i = 0; i < 8; ++i) {
      acc[i] += __shfl_xor(acc[i], 16);
      acc[i] += __shfl_xor(acc[i], 32);
    }
    float dn = dinv[n];
    float v0 = acc[2 * g] * dn;
    float v1 = acc[2 * g + 1] * dn;
    AGGb[(size_t)n * 64 + sl * 4 + g] = packbf(v0, v1);
    s1a += v0;
    s2a = fmaf(v0, v0, s2a);
    s1b += v1;
    s2b = fmaf(v1, v1, s2b);
  }
  __shared__ float sh[4][256];
  int col = sl * 8 + g * 2;
  sh[wave][col] = s1a;
  sh[wave][col + 1] = s1b;
  sh[wave][128 + col] = s2a;
  sh[wave][128 + col + 1] = s2b;
  __syncthreads();
  int t = threadIdx.x;
  float v = sh[0][t] + sh[1][t] + sh[2][t] + sh[3][t];
  atomicAdd(&stats[t], v);
}

// Final standalone norm (layer 2): bf16 AGG -> fp32 d_out. Raw-stats formula, bias folded.
__global__ __launch_bounds__(256) void k_norm(const unsigned* __restrict__ AGGb,
                                              const float* __restrict__ stats,
                                              const float* __restrict__ bias,
                                              const float* __restrict__ gamma,
                                              const float* __restrict__ beta,
                                              const float* __restrict__ alpha,
                                              float* __restrict__ OUT, int N, float invN) {
  int i = blockIdx.x * 256 + threadIdx.x;  // 4-col chunk index
  if (i >= N * 32) return;
  int c4 = i & 31;
  uint2 u = ((const uint2*)AGGb)[i];
  float vv[4] = {blo(u.x), bhi(u.x), blo(u.y), bhi(u.y)};
  float ov[4];
#pragma unroll
  for (int j = 0; j < 4; ++j) {
    int c = c4 * 4 + j;
    float s1 = stats[c] * invN, s2 = stats[128 + c] * invN;
    float b = bias[c], a = alpha[c], g = gamma[c], be = beta[c];
    float mu = s1 + b;
    float E2 = s2 + 2.f * b * s1 + b * b;
    float var = E2 - (2.f * a - a * a) * mu * mu;
    float A = g * rsqrtf(var + EPS_GN);
    float B = be - A * a * mu + A * b;
    float o = fmaf(A, vv[j], B);
    ov[j] = o > 0.f ? o : 0.f;
  }
  ((float4*)OUT)[i] = make_float4(ov[0], ov[1], ov[2], ov[3]);
}

// ---------------- Launch ----------------

extern "C" void kernel_launch(void* const* d_in, const int* in_sizes, int n_in,
                              void* d_out, int out_size, void* d_ws, size_t ws_size,
                              hipStream_t stream) {
  const float* x = (const float*)d_in[0];
  const int* ei = (const int*)d_in[1];
  const float* W0 = (const float*)d_in[2];
  const float* b0 = (const float*)d_in[3];
  const float* W12 = (const float*)d_in[4];
  const float* b12 = (const float*)d_in[5];
  const float* gamma = (const float*)d_in[6];
  const float* beta = (const float*)d_in[7];
  const float* alpha = (const float*)d_in[8];
  float* out = (float*)d_out;

  int N = in_sizes[0] / 4;
  int E = in_sizes[1] / 2;
  const int* srcArr = ei;
  const int* dstArr = ei + E;

  char* w = (char*)d_ws;
  auto alloc = [&](size_t bytes) {
    char* p = w;
    w += (bytes + 255) & ~(size_t)255;
    return p;
  };
  int* cnt = (int*)alloc((size_t)N * 4);
  float* stats = (float*)alloc(3 * 256 * 4);  // [layer][sum(128)|sumsq(128)] - adjacent to cnt
  int* rs = (int*)alloc(((size_t)N + 1) * 4);
  int* cursor = (int*)alloc((size_t)N * 4);
  int* bsum = (int*)alloc(512);
  int* boff = (int*)alloc(512);
  int* csr = (int*)alloc(((size_t)E + 8) * 4);                // src only, padded
  float* dinv = (float*)alloc((size_t)N * 4);
  unsigned* Hb = (unsigned*)alloc(((size_t)N + 1) * 64 * 4);  // bf16 Hs, row N = zeros
  unsigned* AGGb = (unsigned*)alloc((size_t)N * 64 * 4);      // bf16 agg

  // zero cnt + all stats (contiguous region), and the zero-row of Hb
  size_t zlen = (size_t)((char*)stats - (char*)cnt) + 3 * 256 * 4;
  hipMemsetAsync(cnt, 0, zlen, stream);
  hipMemsetAsync(Hb + (size_t)N * 64, 0, 256, stream);

  int nblk = (N + 1023) / 1024;
  k_count_p<<<2048, 256, 0, stream>>>(dstArr, cnt, E, N);
  k_scan1<<<nblk, 256, 0, stream>>>(cnt, rs, bsum, N);
  k_scan2<<<1, 256, 0, stream>>>(bsum, boff, nblk);
  k_finalize<<<(N + 255) / 256, 256, 0, stream>>>(cnt, boff, rs, cursor, dinv, N, E);
  k_fill_p<<<2048, 256, 0, stream>>>(srcArr, dstArr, cursor, csr, E, N);

  float invN = 1.0f / (float)N;
  int gGemm = (N + 15) / 16;
  const uint4* H4 = (const uint4*)Hb;

  // Layer 0
  k_gemm0<<<(N + 3) / 4, 256, 0, stream>>>(x, W0, dinv, Hb, N);
  k_gather<<<2048, 256, 0, stream>>>(H4, rs, csr, dinv, AGGb, stats, N);
  // Layer 1 (norm of layer 0 fused into gemm load)
  k_gemm128n<<<gGemm, 256, 0, stream>>>(AGGb, W12, stats, b0, gamma, beta, alpha, dinv, Hb, N,
                                        invN);
  k_gather<<<2048, 256, 0, stream>>>(H4, rs, csr, dinv, AGGb, stats + 256, N);
  // Layer 2
  k_gemm128n<<<gGemm, 256, 0, stream>>>(AGGb, W12 + 16384, stats + 256, b12, gamma + 128,
                                        beta + 128, alpha + 128, dinv, Hb, N, invN);
  k_gather<<<2048, 256, 0, stream>>>(H4, rs, csr, dinv, AGGb, stats + 512, N);
  // Final norm -> out
  k_norm<<<(N * 32 + 255) / 256, 256, 0, stream>>>(AGGb, stats + 512, b12 + 128, gamma + 256,
                                                   beta + 256, alpha + 256, out, N, invN);
}

// Round 6
// 648.951 us; speedup vs baseline: 1.6546x; 1.2124x over previous
//
#include <hip/hip_runtime.h>

// ConventionalGNN: 3x (GCNConv -> GraphNorm -> ReLU), N=100000 nodes, E=1.6M edges, D=128.
// Hs = dinv*h in bf16; AGG[n] = dinv[n]*(sum Hs[src] + Hs[n]), stored bf16.
// CSR build: XCD-partitioned count/fill. Gather: 16 lanes/row dwordx4, 4-deep prefetch.
// 128x128 GEMM: MFMA 16x16x32 bf16, B-frags from pre-transposed global WbT[n][k],
// prev-layer GraphNorm+ReLU fused into the A-fragment build.

#define EPS_GN 1e-5f

typedef __attribute__((ext_vector_type(8))) short bf16x8;
typedef __attribute__((ext_vector_type(4))) float f32x4;

__device__ __forceinline__ float blo(unsigned u) { return __uint_as_float(u << 16); }
__device__ __forceinline__ float bhi(unsigned u) { return __uint_as_float(u & 0xffff0000u); }
__device__ __forceinline__ unsigned bf16rne(float f) {
  unsigned u = __float_as_uint(f);
  u += 0x7fff + ((u >> 16) & 1);
  return u >> 16;
}
__device__ __forceinline__ unsigned packbf(float x, float y) {
  return bf16rne(x) | (bf16rne(y) << 16);
}

// ---------------- CSR build ----------------

__global__ __launch_bounds__(256) void k_count_p(const int* __restrict__ dst,
                                                 int* __restrict__ cnt, int E, int N) {
  int p = blockIdx.x & 7;
  int lo = (int)((long long)N * p >> 3), hi = (int)((long long)N * (p + 1) >> 3);
  int stride = (gridDim.x >> 3) * 256;
  for (int e = (blockIdx.x >> 3) * 256 + threadIdx.x; e < E; e += stride) {
    int d = dst[e];
    if (d >= lo && d < hi) atomicAdd(&cnt[d], 1);
  }
}

__global__ __launch_bounds__(256) void k_scan1(const int* __restrict__ cnt,
                                               int* __restrict__ rs,
                                               int* __restrict__ bsum, int N) {
  __shared__ int s[256];
  int t = threadIdx.x;
  int base = blockIdx.x * 1024 + t * 4;
  int c0 = (base + 0 < N) ? cnt[base + 0] : 0;
  int c1 = (base + 1 < N) ? cnt[base + 1] : 0;
  int c2 = (base + 2 < N) ? cnt[base + 2] : 0;
  int c3 = (base + 3 < N) ? cnt[base + 3] : 0;
  int tsum = c0 + c1 + c2 + c3;
  s[t] = tsum;
  __syncthreads();
  for (int off = 1; off < 256; off <<= 1) {
    int v = (t >= off) ? s[t - off] : 0;
    __syncthreads();
    s[t] += v;
    __syncthreads();
  }
  int excl = s[t] - tsum;
  if (t == 255) bsum[blockIdx.x] = s[255];
  int e0 = excl, e1 = e0 + c0, e2 = e1 + c1, e3 = e2 + c2;
  if (base + 0 < N) rs[base + 0] = e0;
  if (base + 1 < N) rs[base + 1] = e1;
  if (base + 2 < N) rs[base + 2] = e2;
  if (base + 3 < N) rs[base + 3] = e3;
}

__global__ __launch_bounds__(256) void k_scan2(const int* __restrict__ bsum,
                                               int* __restrict__ boff, int nblk) {
  __shared__ int s[256];
  int t = threadIdx.x;
  int v0 = (t < nblk) ? bsum[t] : 0;
  s[t] = v0;
  __syncthreads();
  for (int off = 1; off < 256; off <<= 1) {
    int v = (t >= off) ? s[t - off] : 0;
    __syncthreads();
    s[t] += v;
    __syncthreads();
  }
  if (t < nblk) boff[t] = s[t] - v0;
}

__global__ __launch_bounds__(256) void k_finalize(const int* __restrict__ cnt,
                                                  const int* __restrict__ boff,
                                                  int* __restrict__ rs,
                                                  int* __restrict__ cursor,
                                                  float* __restrict__ dinv, int N, int E) {
  int i = blockIdx.x * 256 + threadIdx.x;
  if (i == 0) rs[N] = E;
  if (i < N) {
    int v = rs[i] + boff[i >> 10];
    rs[i] = v;
    cursor[i] = v;
    dinv[i] = rsqrtf((float)cnt[i] + 1.0f);
  }
}

__global__ __launch_bounds__(256) void k_fill_p(const int* __restrict__ src,
                                                const int* __restrict__ dst,
                                                int* __restrict__ cursor,
                                                int* __restrict__ csr, int E, int N) {
  int p = blockIdx.x & 7;
  int lo = (int)((long long)N * p >> 3), hi = (int)((long long)N * (p + 1) >> 3);
  int stride = (gridDim.x >> 3) * 256;
  for (int e = (blockIdx.x >> 3) * 256 + threadIdx.x; e < E; e += stride) {
    int d = dst[e];
    if (d >= lo && d < hi) {
      int pos = atomicAdd(&cursor[d], 1);
      csr[pos] = src[e];
    }
  }
}

// ---------------- Weight transpose (once per call) ----------------

// WbT[layer][n][k] = bf16(W12[layer][k][n]); output-coalesced.
__global__ __launch_bounds__(256) void k_wt(const float* __restrict__ W12,
                                            unsigned short* __restrict__ WbT) {
  int o = blockIdx.x * 256 + threadIdx.x;  // [0, 2*16384)
  int layer = o >> 14, r = o & 16383;
  int n = r >> 7, k = r & 127;
  WbT[o] = (unsigned short)bf16rne(W12[layer * 16384 + k * 128 + n]);
}

// ---------------- Layer kernels ----------------

// Hs(bf16) = dinv * (X @ W0). 4 rows/block; thread = 1 row x 2 cols.
__global__ __launch_bounds__(256) void k_gemm0(const float* __restrict__ X,
                                               const float* __restrict__ W,
                                               const float* __restrict__ dinv,
                                               unsigned* __restrict__ H, int N) {
  __shared__ float Ws[4 * 128];
  int t = threadIdx.x;
  if (t < 128) {
    Ws[t] = W[t];
    Ws[128 + t] = W[128 + t];
    Ws[256 + t] = W[256 + t];
    Ws[384 + t] = W[384 + t];
  }
  __syncthreads();
  int r = t >> 6, l = t & 63;
  int row = blockIdx.x * 4 + r;
  if (row >= N) return;
  float4 xv = ((const float4*)X)[row];
  float di = dinv[row];
  int c0 = 2 * l, c1 = 2 * l + 1;
  float v0 = xv.x * Ws[c0] + xv.y * Ws[128 + c0] + xv.z * Ws[256 + c0] + xv.w * Ws[384 + c0];
  float v1 = xv.x * Ws[c1] + xv.y * Ws[128 + c1] + xv.z * Ws[256 + c1] + xv.w * Ws[384 + c1];
  H[(size_t)row * 64 + l] = packbf(di * v0, di * v1);
}

// Hs(bf16) = dinv * (relu(norm(AGGb)) @ W) via MFMA 16x16x32 bf16.
// Wave = 16-row tile. A-frag: lane l -> row r0+(l&15), k = (l>>4)*8..+7 per 32-K slab,
// norm+relu applied during build. B-frag: 8 contiguous bf16 from WbT[n][k] (global, L2).
// D: lane l -> col (l&15), row (l>>4)*4+reg (m89-verified).
__global__ __launch_bounds__(256, 4) void k_gemm_mfma(const unsigned* __restrict__ AGGb,
                                                      const unsigned short* __restrict__ WbT,
                                                      const float* __restrict__ stats,
                                                      const float* __restrict__ bias,
                                                      const float* __restrict__ gamma,
                                                      const float* __restrict__ beta,
                                                      const float* __restrict__ alpha,
                                                      const float* __restrict__ dinv,
                                                      unsigned* __restrict__ H, int N,
                                                      float invN) {
  __shared__ float As[128], Bs[128];
  int t = threadIdx.x;
  if (t < 128) {
    float s1 = stats[t] * invN, s2 = stats[128 + t] * invN;
    float b = bias[t], a = alpha[t], g = gamma[t], be = beta[t];
    float mu = s1 + b;                     // mean of (agg + b)
    float E2 = s2 + 2.f * b * s1 + b * b;  // E[(agg+b)^2]
    float var = E2 - (2.f * a - a * a) * mu * mu;
    float A = g * rsqrtf(var + EPS_GN);
    As[t] = A;
    Bs[t] = be - A * a * mu + A * b;  // normed = A*agg + B
  }
  __syncthreads();
  int wv = t >> 6, l = t & 63;
  int r0 = blockIdx.x * 64 + wv * 16;
  if (r0 >= N) return;
  int m = l & 15, kb = l >> 4;

  f32x4 acc[8];
#pragma unroll
  for (int nt = 0; nt < 8; ++nt) acc[nt] = (f32x4){0.f, 0.f, 0.f, 0.f};

  const uint4* Arow = (const uint4*)(AGGb + (size_t)(r0 + m) * 64);

#pragma unroll
  for (int ks = 0; ks < 4; ++ks) {
    int k0 = ks * 32 + kb * 8;
    uint4 a_raw = Arow[ks * 4 + kb];
    // norm params for this lane's 8 k's (LDS broadcast within 16-lane groups)
    float4 A0 = *reinterpret_cast<const float4*>(&As[k0]);
    float4 A1 = *reinterpret_cast<const float4*>(&As[k0 + 4]);
    float4 B0 = *reinterpret_cast<const float4*>(&Bs[k0]);
    float4 B1 = *reinterpret_cast<const float4*>(&Bs[k0 + 4]);
    // B fragments for the 8 N-tiles (global, L2-resident; 16 dense lines per inst)
    bf16x8 bf[8];
#pragma unroll
    for (int nt = 0; nt < 8; ++nt)
      bf[nt] = *reinterpret_cast<const bf16x8*>(WbT + (size_t)(nt * 16 + m) * 128 + k0);
    // build normed+relu'd A fragment
    float xr[8] = {blo(a_raw.x), bhi(a_raw.x), blo(a_raw.y), bhi(a_raw.y),
                   blo(a_raw.z), bhi(a_raw.z), blo(a_raw.w), bhi(a_raw.w)};
    float Aa[8] = {A0.x, A0.y, A0.z, A0.w, A1.x, A1.y, A1.z, A1.w};
    float Bb[8] = {B0.x, B0.y, B0.z, B0.w, B1.x, B1.y, B1.z, B1.w};
    bf16x8 af;
#pragma unroll
    for (int j = 0; j < 8; ++j) {
      float v = fmaf(Aa[j], xr[j], Bb[j]);
      v = v > 0.f ? v : 0.f;
      af[j] = (short)bf16rne(v);
    }
#pragma unroll
    for (int nt = 0; nt < 8; ++nt)
      acc[nt] = __builtin_amdgcn_mfma_f32_16x16x32_bf16(af, bf[nt], acc[nt], 0, 0, 0);
  }

  // epilogue: scale by dinv(row), pack pairs of adjacent cols via shfl, even lanes store.
  float dn[4];
#pragma unroll
  for (int r = 0; r < 4; ++r) dn[r] = dinv[r0 + kb * 4 + r];
  bool even = (l & 1) == 0;
#pragma unroll
  for (int nt = 0; nt < 8; ++nt) {
#pragma unroll
    for (int r = 0; r < 4; ++r) {
      float v = acc[nt][r] * dn[r];
      float pv = __shfl_xor(v, 1);
      if (even) {
        unsigned word = packbf(v, pv);
        H[(size_t)(r0 + kb * 4 + r) * 64 + nt * 8 + (m >> 1)] = word;
      }
    }
  }
}

// AGGb[n](bf16) = dinv[n] * (Hs[n] + sum_{e in csr[n]} Hs[src]). Hs bf16, rows 256B (16 uint4).
// Wave = 1 node; 16-lane group g handles virtual edge b*4+g-1 (-1 = self, >=len = zero row N).
// 4-deep rotating prefetch; shfl_xor butterfly combine; fused per-block column stats (fp32).
__global__ __launch_bounds__(256) void k_gather(const uint4* __restrict__ H4,
                                                const int* __restrict__ rs,
                                                const int* __restrict__ csr,
                                                const float* __restrict__ dinv,
                                                unsigned* __restrict__ AGGb,
                                                float* __restrict__ stats, int N) {
  int wave = threadIdx.x >> 6, lane = threadIdx.x & 63;
  int g = lane >> 4, sl = lane & 15;
  float s1a = 0.f, s1b = 0.f, s2a = 0.f, s2b = 0.f;
  for (int n = blockIdx.x * 4 + wave; n < N; n += gridDim.x * 4) {
    int j0 = rs[n], j1 = rs[n + 1];
    int len = j1 - j0;
    int nb = (len + 4) >> 2;  // batches covering len+1 virtual edges
    float acc[8];
#pragma unroll
    for (int i = 0; i < 8; ++i) acc[i] = 0.f;

    auto vsrc = [&](int b) -> int {
      int idx = b * 4 + g - 1;
      int jj = j0 + idx;
      jj = min(jj, j1 - 1);
      jj = max(jj, j0);
      int c = csr[jj];
      return (idx < 0) ? n : ((idx < len) ? c : N);
    };

    uint4 hA = H4[(size_t)vsrc(0) * 16 + sl];
    uint4 hB, hC, hD, hE;
    if (nb > 1) hB = H4[(size_t)vsrc(1) * 16 + sl];
    if (nb > 2) hC = H4[(size_t)vsrc(2) * 16 + sl];
    if (nb > 3) hD = H4[(size_t)vsrc(3) * 16 + sl];
    for (int b = 0; b < nb; ++b) {
      if (b + 4 < nb) hE = H4[(size_t)vsrc(b + 4) * 16 + sl];
      unsigned uu[4] = {hA.x, hA.y, hA.z, hA.w};
#pragma unroll
      for (int i = 0; i < 4; ++i) {
        acc[2 * i] += blo(uu[i]);
        acc[2 * i + 1] += bhi(uu[i]);
      }
      hA = hB;
      hB = hC;
      hC = hD;
      hD = hE;
    }
    // butterfly: every lane ends with the full column sums for its sl-slice
#pragma unroll
    for (int i = 0; i < 8; ++i) {
      acc[i] += __shfl_xor(acc[i], 16);
      acc[i] += __shfl_xor(acc[i], 32);
    }
    float dnv = dinv[n];
    float v0 = acc[2 * g] * dnv;
    float v1 = acc[2 * g + 1] * dnv;
    AGGb[(size_t)n * 64 + sl * 4 + g] = packbf(v0, v1);
    s1a += v0;
    s2a = fmaf(v0, v0, s2a);
    s1b += v1;
    s2b = fmaf(v1, v1, s2b);
  }
  __shared__ float sh[4][256];
  int col = sl * 8 + g * 2;
  sh[wave][col] = s1a;
  sh[wave][col + 1] = s1b;
  sh[wave][128 + col] = s2a;
  sh[wave][128 + col + 1] = s2b;
  __syncthreads();
  int t = threadIdx.x;
  float v = sh[0][t] + sh[1][t] + sh[2][t] + sh[3][t];
  atomicAdd(&stats[t], v);
}

// Final standalone norm (layer 2): bf16 AGG -> fp32 d_out. Raw-stats formula, bias folded.
__global__ __launch_bounds__(256) void k_norm(const unsigned* __restrict__ AGGb,
                                              const float* __restrict__ stats,
                                              const float* __restrict__ bias,
                                              const float* __restrict__ gamma,
                                              const float* __restrict__ beta,
                                              const float* __restrict__ alpha,
                                              float* __restrict__ OUT, int N, float invN) {
  int i = blockIdx.x * 256 + threadIdx.x;  // 4-col chunk index
  if (i >= N * 32) return;
  int c4 = i & 31;
  uint2 u = ((const uint2*)AGGb)[i];
  float vv[4] = {blo(u.x), bhi(u.x), blo(u.y), bhi(u.y)};
  float ov[4];
#pragma unroll
  for (int j = 0; j < 4; ++j) {
    int c = c4 * 4 + j;
    float s1 = stats[c] * invN, s2 = stats[128 + c] * invN;
    float b = bias[c], a = alpha[c], g = gamma[c], be = beta[c];
    float mu = s1 + b;
    float E2 = s2 + 2.f * b * s1 + b * b;
    float var = E2 - (2.f * a - a * a) * mu * mu;
    float A = g * rsqrtf(var + EPS_GN);
    float B = be - A * a * mu + A * b;
    float o = fmaf(A, vv[j], B);
    ov[j] = o > 0.f ? o : 0.f;
  }
  ((float4*)OUT)[i] = make_float4(ov[0], ov[1], ov[2], ov[3]);
}

// ---------------- Launch ----------------

extern "C" void kernel_launch(void* const* d_in, const int* in_sizes, int n_in,
                              void* d_out, int out_size, void* d_ws, size_t ws_size,
                              hipStream_t stream) {
  const float* x = (const float*)d_in[0];
  const int* ei = (const int*)d_in[1];
  const float* W0 = (const float*)d_in[2];
  const float* b0 = (const float*)d_in[3];
  const float* W12 = (const float*)d_in[4];
  const float* b12 = (const float*)d_in[5];
  const float* gamma = (const float*)d_in[6];
  const float* beta = (const float*)d_in[7];
  const float* alpha = (const float*)d_in[8];
  float* out = (float*)d_out;

  int N = in_sizes[0] / 4;
  int E = in_sizes[1] / 2;
  const int* srcArr = ei;
  const int* dstArr = ei + E;

  char* w = (char*)d_ws;
  auto alloc = [&](size_t bytes) {
    char* p = w;
    w += (bytes + 255) & ~(size_t)255;
    return p;
  };
  int* cnt = (int*)alloc((size_t)N * 4);
  float* stats = (float*)alloc(3 * 256 * 4);  // [layer][sum(128)|sumsq(128)] - adjacent to cnt
  int* rs = (int*)alloc(((size_t)N + 1) * 4);
  int* cursor = (int*)alloc((size_t)N * 4);
  int* bsum = (int*)alloc(512);
  int* boff = (int*)alloc(512);
  unsigned short* WbT = (unsigned short*)alloc(2 * 16384 * 2);  // bf16 W^T, both layers
  int* csr = (int*)alloc(((size_t)E + 8) * 4);                  // src only, padded
  float* dinv = (float*)alloc((size_t)N * 4);
  unsigned* Hb = (unsigned*)alloc(((size_t)N + 1) * 64 * 4);    // bf16 Hs, row N = zeros
  unsigned* AGGb = (unsigned*)alloc((size_t)N * 64 * 4);        // bf16 agg

  // zero cnt + all stats (contiguous region), and the zero-row of Hb
  size_t zlen = (size_t)((char*)stats - (char*)cnt) + 3 * 256 * 4;
  hipMemsetAsync(cnt, 0, zlen, stream);
  hipMemsetAsync(Hb + (size_t)N * 64, 0, 256, stream);

  int nblk = (N + 1023) / 1024;
  k_wt<<<128, 256, 0, stream>>>(W12, WbT);
  k_count_p<<<2048, 256, 0, stream>>>(dstArr, cnt, E, N);
  k_scan1<<<nblk, 256, 0, stream>>>(cnt, rs, bsum, N);
  k_scan2<<<1, 256, 0, stream>>>(bsum, boff, nblk);
  k_finalize<<<(N + 255) / 256, 256, 0, stream>>>(cnt, boff, rs, cursor, dinv, N, E);
  k_fill_p<<<2048, 256, 0, stream>>>(srcArr, dstArr, cursor, csr, E, N);

  float invN = 1.0f / (float)N;
  int gGemm = (N + 63) / 64;
  const uint4* H4 = (const uint4*)Hb;

  // Layer 0
  k_gemm0<<<(N + 3) / 4, 256, 0, stream>>>(x, W0, dinv, Hb, N);
  k_gather<<<2048, 256, 0, stream>>>(H4, rs, csr, dinv, AGGb, stats, N);
  // Layer 1 (norm of layer 0 fused into A-fragment build)
  k_gemm_mfma<<<gGemm, 256, 0, stream>>>(AGGb, WbT, stats, b0, gamma, beta, alpha, dinv, Hb, N,
                                         invN);
  k_gather<<<2048, 256, 0, stream>>>(H4, rs, csr, dinv, AGGb, stats + 256, N);
  // Layer 2
  k_gemm_mfma<<<gGemm, 256, 0, stream>>>(AGGb, WbT + 16384, stats + 256, b12, gamma + 128,
                                         beta + 128, alpha + 128, dinv, Hb, N, invN);
  k_gather<<<2048, 256, 0, stream>>>(H4, rs, csr, dinv, AGGb, stats + 512, N);
  // Final norm -> out
  k_norm<<<(N * 32 + 255) / 256, 256, 0, stream>>>(AGGb, stats + 512, b12 + 128, gamma + 256,
                                                   beta + 256, alpha + 256, out, N, invN);
}